// Round 2
// baseline (4803.340 us; speedup 1.0000x reference)
//
#include <hip/hip_runtime.h>
#include <hip/hip_bf16.h>

// ProteinLigandAttention: D=256, B=256 complexes, 3 iterations.
// All float tensors are fp32 (reference dtype). Scopes may arrive as int32 or
// int64 — normalized at runtime by conv_scope. State/qkv kept fp32 (accuracy);
// bf16 qkv fallback only if ws_size is too small.

#define DD 256
#define NCPLX 256
#define NITER 3

using bf16 = __hip_bfloat16;

__device__ __forceinline__ float4 ld4(const float* p) {
    return *reinterpret_cast<const float4*>(p);
}
__device__ __forceinline__ float4 ld4(const bf16* p) {
    ushort4 u = *reinterpret_cast<const ushort4*>(p);
    float4 r;
    r.x = __uint_as_float((unsigned int)u.x << 16);
    r.y = __uint_as_float((unsigned int)u.y << 16);
    r.z = __uint_as_float((unsigned int)u.z << 16);
    r.w = __uint_as_float((unsigned int)u.w << 16);
    return r;
}
__device__ __forceinline__ void st1(float* p, float v) { *p = v; }
__device__ __forceinline__ void st1(bf16* p, float v) { *p = __float2bfloat16(v); }

// Normalize scopes to int32 {start,cnt} pairs. Detect int64 input at runtime:
// for the int32 interpretation, last segment must end exactly at n.
__global__ void conv_scope(const int* __restrict__ lig, const int* __restrict__ res,
                           int nA, int nR, int* __restrict__ ligN, int* __restrict__ resN)
{
    const int b = threadIdx.x;  // single block of 256
    const bool l64 = (lig[2 * (NCPLX - 1)] + lig[2 * (NCPLX - 1) + 1]) != nA;
    const bool r64 = (res[2 * (NCPLX - 1)] + res[2 * (NCPLX - 1) + 1]) != nR;
    ligN[2 * b]     = l64 ? lig[4 * b]     : lig[2 * b];
    ligN[2 * b + 1] = l64 ? lig[4 * b + 2] : lig[2 * b + 1];
    resN[2 * b]     = r64 ? res[4 * b]     : res[2 * b];
    resN[2 * b + 1] = r64 ? res[4 * b + 2] : res[2 * b + 1];
}

// scaleA[a] = 1/r_cnt(complex of a); scaleR[r] = 1/a_cnt(complex of r)
__global__ void scales_k(const int* __restrict__ lig, const int* __restrict__ res,
                         float* __restrict__ sA, float* __restrict__ sR)
{
    int b = blockIdx.x, t = threadIdx.x;
    int a0 = lig[2 * b], ac = lig[2 * b + 1];
    int r0 = res[2 * b], rc = res[2 * b + 1];
    float va = 1.0f / (float)rc;
    float vr = 1.0f / (float)ac;
    for (int i = t; i < ac; i += blockDim.x) sA[a0 + i] = va;
    for (int i = t; i < rc; i += blockDim.x) sR[r0 + i] = vr;
}

// Y[n x 256] = [leaky](X[n x 256] @ W[256 x 256]) [* rowscale] [+ resid]
// 64x64 tile per 256-thread block, K-chunks of 16, 4x4 per thread.
template <typename XT, typename YT, bool LEAKY, bool SCALE, bool RESID>
__global__ __launch_bounds__(256) void gemm256(
    const XT* __restrict__ X, const float* __restrict__ W, YT* __restrict__ Y,
    const float* __restrict__ resid, const float* __restrict__ rowscale, int n)
{
    __shared__ float Xs[64][20];
    __shared__ float Ws[16][68];
    const int t = threadIdx.x;
    const int row0 = blockIdx.x * 64;
    const int col0 = blockIdx.y * 64;
    const int ty = t >> 4, tx = t & 15;
    const int lxr = t >> 2, lxk = (t & 3) << 2;
    const int lwk = t >> 4, lwc = (t & 15) << 2;

    float acc[4][4] = {};

    for (int k0 = 0; k0 < DD; k0 += 16) {
        {
            int gr = row0 + lxr;
            float4 xv = make_float4(0.f, 0.f, 0.f, 0.f);
            if (gr < n) xv = ld4(X + (size_t)gr * DD + k0 + lxk);
            Xs[lxr][lxk + 0] = xv.x; Xs[lxr][lxk + 1] = xv.y;
            Xs[lxr][lxk + 2] = xv.z; Xs[lxr][lxk + 3] = xv.w;
        }
        {
            float4 wv = ld4(W + (size_t)(k0 + lwk) * DD + col0 + lwc);
            Ws[lwk][lwc + 0] = wv.x; Ws[lwk][lwc + 1] = wv.y;
            Ws[lwk][lwc + 2] = wv.z; Ws[lwk][lwc + 3] = wv.w;
        }
        __syncthreads();
#pragma unroll
        for (int kk = 0; kk < 16; ++kk) {
            float a0 = Xs[ty * 4 + 0][kk];
            float a1 = Xs[ty * 4 + 1][kk];
            float a2 = Xs[ty * 4 + 2][kk];
            float a3 = Xs[ty * 4 + 3][kk];
            float b0 = Ws[kk][tx * 4 + 0];
            float b1 = Ws[kk][tx * 4 + 1];
            float b2 = Ws[kk][tx * 4 + 2];
            float b3 = Ws[kk][tx * 4 + 3];
            acc[0][0] += a0 * b0; acc[0][1] += a0 * b1; acc[0][2] += a0 * b2; acc[0][3] += a0 * b3;
            acc[1][0] += a1 * b0; acc[1][1] += a1 * b1; acc[1][2] += a1 * b2; acc[1][3] += a1 * b3;
            acc[2][0] += a2 * b0; acc[2][1] += a2 * b1; acc[2][2] += a2 * b2; acc[2][3] += a2 * b3;
            acc[3][0] += a3 * b0; acc[3][1] += a3 * b1; acc[3][2] += a3 * b2; acc[3][3] += a3 * b3;
        }
        __syncthreads();
    }

#pragma unroll
    for (int i = 0; i < 4; ++i) {
        int gr = row0 + ty * 4 + i;
        if (gr >= n) continue;
        float sc = SCALE ? rowscale[gr] : 1.0f;
#pragma unroll
        for (int j = 0; j < 4; ++j) {
            float v = acc[i][j];
            if (LEAKY) v = (v >= 0.f) ? v : 0.1f * v;   // leaky BEFORE /cnt (ref order)
            if (SCALE) v *= sc;
            size_t off = (size_t)gr * DD + col0 + tx * 4 + j;
            if (RESID) v += resid[off];
            st1(Y + off, v);
        }
    }
}

// O[q,:] = sum_r sigmoid(Q[q,:] . K[r,:]) * V[r,:]   (ragged per complex)
// One wave per query row; lane owns 4 columns. O may alias Q (each wave reads
// only its own Q row, up front, and writes only that row).
template <typename T>
__global__ __launch_bounds__(256) void attn_sig(
    const T* __restrict__ Q, const T* __restrict__ K, const T* __restrict__ V,
    T* __restrict__ O, const int* __restrict__ qs, const int* __restrict__ ks)
{
    const int b = blockIdx.x;
    const int w = threadIdx.x >> 6;
    const int lane = threadIdx.x & 63;
    const int qc = qs[2 * b + 1];
    const int qi = blockIdx.y * 4 + w;
    if (qi >= qc) return;
    const int q0 = qs[2 * b];
    const int k0 = ks[2 * b];
    const int kc = ks[2 * b + 1];

    const size_t qoff = (size_t)(q0 + qi) * DD + lane * 4;
    float4 q = ld4(Q + qoff);
    float ax = 0.f, ay = 0.f, az = 0.f, aw = 0.f;

    for (int r = 0; r < kc; ++r) {
        size_t koff = (size_t)(k0 + r) * DD + lane * 4;
        float4 kf = ld4(K + koff);
        float4 vf = ld4(V + koff);
        float part = q.x * kf.x + q.y * kf.y + q.z * kf.z + q.w * kf.w;
#pragma unroll
        for (int off = 32; off; off >>= 1) part += __shfl_xor(part, off, 64);
        float s = 1.0f / (1.0f + __expf(-part));
        ax += s * vf.x; ay += s * vf.y; az += s * vf.z; aw += s * vf.w;
    }
    st1(O + qoff + 0, ax);
    st1(O + qoff + 1, ay);
    st1(O + qoff + 2, az);
    st1(O + qoff + 3, aw);
}

template <typename T>
static void run_pipeline(const float* fatoms, const float* fres, const float* const* W,
                         const int* lig_raw, const int* res_raw,
                         float* out, int nA, int nR, char* ws, hipStream_t stream)
{
    char* p = ws;
    auto carve = [&](size_t bytes) -> void* {
        void* r = (void*)p;
        p += (bytes + 255) & ~(size_t)255;
        return r;
    };
    float* A  = (float*)carve((size_t)nA * DD * 4);
    float* R  = (float*)carve((size_t)nR * DD * 4);
    T* AQ = (T*)carve((size_t)nA * DD * sizeof(T));   // becomes attn output
    T* AK = (T*)carve((size_t)nA * DD * sizeof(T));
    T* AV = (T*)carve((size_t)nA * DD * sizeof(T));
    T* RQ = (T*)carve((size_t)nR * DD * sizeof(T));   // becomes attn output
    T* RK = (T*)carve((size_t)nR * DD * sizeof(T));
    T* RV = (T*)carve((size_t)nR * DD * sizeof(T));
    float* sA = (float*)carve((size_t)nA * 4);
    float* sR = (float*)carve((size_t)nR * 4);
    int* ligN = (int*)carve(NCPLX * 2 * 4);
    int* resN = (int*)carve(NCPLX * 2 * 4);

    const dim3 blk(256);
    const dim3 gridA((nA + 63) / 64, 4);
    const dim3 gridR((nR + 63) / 64, 4);

    conv_scope<<<1, NCPLX, 0, stream>>>(lig_raw, res_raw, nA, nR, ligN, resN);
    scales_k<<<NCPLX, 256, 0, stream>>>(ligN, resN, sA, sR);

    // input transforms: A = leaky(fatoms @ W_lig_t), R = leaky(fres @ W_res_t)
    gemm256<float, float, true, false, false><<<gridA, blk, 0, stream>>>(fatoms, W[0], A, nullptr, nullptr, nA);
    gemm256<float, float, true, false, false><<<gridR, blk, 0, stream>>>(fres,   W[1], R, nullptr, nullptr, nR);

    for (int it = 0; it < NITER; ++it) {
        gemm256<float, T, false, false, false><<<gridA, blk, 0, stream>>>(A, W[2], AQ, nullptr, nullptr, nA);
        gemm256<float, T, false, false, false><<<gridA, blk, 0, stream>>>(A, W[3], AK, nullptr, nullptr, nA);
        gemm256<float, T, false, false, false><<<gridA, blk, 0, stream>>>(A, W[4], AV, nullptr, nullptr, nA);
        gemm256<float, T, false, false, false><<<gridR, blk, 0, stream>>>(R, W[6], RQ, nullptr, nullptr, nR);
        gemm256<float, T, false, false, false><<<gridR, blk, 0, stream>>>(R, W[7], RK, nullptr, nullptr, nR);
        gemm256<float, T, false, false, false><<<gridR, blk, 0, stream>>>(R, W[8], RV, nullptr, nullptr, nR);

        attn_sig<T><<<dim3(NCPLX, 16),  blk, 0, stream>>>(AQ, RK, RV, AQ, ligN, resN);
        attn_sig<T><<<dim3(NCPLX, 128), blk, 0, stream>>>(RQ, AK, AV, RQ, resN, ligN);

        if (it < NITER - 1) {
            gemm256<T, float, true, true, true><<<gridA, blk, 0, stream>>>(AQ, W[5], A, A, sA, nA);
            gemm256<T, float, true, true, true><<<gridR, blk, 0, stream>>>(RQ, W[9], R, R, sR, nR);
        } else {
            gemm256<T, float, true, true, true><<<gridA, blk, 0, stream>>>(AQ, W[5], out, A, sA, nA);
            gemm256<T, float, true, true, true><<<gridR, blk, 0, stream>>>(RQ, W[9], out + (size_t)nA * DD, R, sR, nR);
        }
    }
}

extern "C" void kernel_launch(void* const* d_in, const int* in_sizes, int n_in,
                              void* d_out, int out_size, void* d_ws, size_t ws_size,
                              hipStream_t stream)
{
    const float* fatoms = (const float*)d_in[0];
    const float* fres   = (const float*)d_in[1];
    const float* W[10] = {
        (const float*)d_in[2],  // W_lig_t
        (const float*)d_in[3],  // W_res_t
        (const float*)d_in[4],  // WQl
        (const float*)d_in[5],  // WKl
        (const float*)d_in[6],  // WVl
        (const float*)d_in[7],  // WOl
        (const float*)d_in[8],  // WQr
        (const float*)d_in[9],  // WKr
        (const float*)d_in[10], // WVr
        (const float*)d_in[11], // WOr
    };
    const int* lig_raw = (const int*)d_in[12];
    const int* res_raw = (const int*)d_in[13];

    const int nA = in_sizes[0] / DD;
    const int nR = in_sizes[1] / DD;
    (void)n_in; (void)out_size;

    // ws requirement: state fp32 (always) + 3x qkv per side + scales + scopes
    const size_t stateB = (((size_t)nA * DD * 4 + 255) & ~(size_t)255)
                        + (((size_t)nR * DD * 4 + 255) & ~(size_t)255);
    const size_t miscB = (((size_t)nA * 4 + 255) & ~(size_t)255)
                       + (((size_t)nR * 4 + 255) & ~(size_t)255) + 2 * 2048 + 4096;
    const size_t qkvF32 = 3 * ((((size_t)nA * DD * 4 + 255) & ~(size_t)255)
                             + (((size_t)nR * DD * 4 + 255) & ~(size_t)255));
    const bool f32ok = ws_size >= stateB + qkvF32 + miscB;

    if (f32ok)
        run_pipeline<float>(fatoms, fres, W, lig_raw, res_raw, (float*)d_out, nA, nR, (char*)d_ws, stream);
    else
        run_pipeline<bf16>(fatoms, fres, W, lig_raw, res_raw, (float*)d_out, nA, nR, (char*)d_ws, stream);
}

// Round 3
// 1148.480 us; speedup vs baseline: 4.1823x; 4.1823x over previous
//
#include <hip/hip_runtime.h>
#include <hip/hip_bf16.h>

// ProteinLigandAttention: D=256, B=256, 3 iters.
// fp32 state + fp32 input transforms (accuracy-critical path);
// bf16 MFMA for all projections / epilogues / attention (error-attenuated by /cnt).

#define DD 256
#define NCPLX 256
#define NITER 3

using s8v = __attribute__((ext_vector_type(8))) short;   // 8 bf16 = 4 VGPR
using f4v = __attribute__((ext_vector_type(4))) float;   // MFMA C/D

__device__ __forceinline__ short f2bf(float f) {
    union { float f; unsigned u; } v; v.f = f;
    unsigned r = v.u + 0x7fffu + ((v.u >> 16) & 1u);   // RNE
    return (short)(r >> 16);
}
__device__ __forceinline__ float bf2f(short s) {
    union { unsigned u; float f; } v; v.u = ((unsigned)(unsigned short)s) << 16;
    return v.f;
}
__device__ __forceinline__ float4 ld4f(const float* p) { return *reinterpret_cast<const float4*>(p); }

// ---------- scope normalization (int32 vs int64) ----------
__global__ void conv_scope(const int* __restrict__ lig, const int* __restrict__ res,
                           int nA, int nR, int* __restrict__ ligN, int* __restrict__ resN)
{
    const int b = threadIdx.x;
    const bool l64 = (lig[2*(NCPLX-1)] + lig[2*(NCPLX-1)+1]) != nA;
    const bool r64 = (res[2*(NCPLX-1)] + res[2*(NCPLX-1)+1]) != nR;
    ligN[2*b]   = l64 ? lig[4*b]   : lig[2*b];
    ligN[2*b+1] = l64 ? lig[4*b+2] : lig[2*b+1];
    resN[2*b]   = r64 ? res[4*b]   : res[2*b];
    resN[2*b+1] = r64 ? res[4*b+2] : res[2*b+1];
}

__global__ void scales_k(const int* __restrict__ lig, const int* __restrict__ res,
                         float* __restrict__ sA, float* __restrict__ sR)
{
    int b = blockIdx.x, t = threadIdx.x;
    int a0 = lig[2*b], ac = lig[2*b+1];
    int r0 = res[2*b], rc = res[2*b+1];
    float va = 1.0f / (float)rc, vr = 1.0f / (float)ac;
    for (int i = t; i < ac; i += blockDim.x) sA[a0+i] = va;
    for (int i = t; i < rc; i += blockDim.x) sR[r0+i] = vr;
}

// ---------- one-time weight convert+transpose: Wt[n][k] bf16 ----------
__global__ __launch_bounds__(256) void wtrans(
    const float* w0, const float* w1, const float* w2, const float* w3,
    const float* w4, const float* w5, const float* w6, const float* w7,
    short* __restrict__ out)
{
    const float* W;
    switch (blockIdx.x) {
        case 0: W = w0; break; case 1: W = w1; break; case 2: W = w2; break; case 3: W = w3; break;
        case 4: W = w4; break; case 5: W = w5; break; case 6: W = w6; break; default: W = w7; break;
    }
    short* O = out + (size_t)blockIdx.x * 65536;
    const int tile = blockIdx.y;             // 64 tiles of 32x32
    const int tr = (tile >> 3) * 32, tc = (tile & 7) * 32;
    __shared__ short T[32 * 34];
    const int t = threadIdx.x;
#pragma unroll
    for (int i = 0; i < 4; ++i) {
        int idx = t + i * 256, r = idx >> 5, c = idx & 31;
        T[c * 34 + r] = f2bf(W[(size_t)(tr + r) * 256 + tc + c]);
    }
    __syncthreads();
#pragma unroll
    for (int i = 0; i < 4; ++i) {
        int idx = t + i * 256, nn = idx >> 5, kk = idx & 31;
        O[(size_t)(tc + nn) * 256 + tr + kk] = T[nn * 34 + kk];
    }
}

// ---------- fp32 vector GEMM for input transforms (accuracy-critical) ----------
// Y = leaky(X @ W), writes fp32 state + bf16 shadow. 64x64 tile / 256 threads.
__global__ __launch_bounds__(256) void gemm_xform(
    const float* __restrict__ X, const float* __restrict__ W,
    float* __restrict__ Yf, short* __restrict__ Yb, int n)
{
    __shared__ float Xs[64][20];
    __shared__ float Ws[16][68];
    const int t = threadIdx.x;
    const int row0 = blockIdx.x * 64, col0 = blockIdx.y * 64;
    const int ty = t >> 4, tx = t & 15;
    const int lxr = t >> 2, lxk = (t & 3) << 2;
    const int lwk = t >> 4, lwc = (t & 15) << 2;
    float acc[4][4] = {};
    for (int k0 = 0; k0 < DD; k0 += 16) {
        {
            int gr = row0 + lxr;
            float4 xv = make_float4(0.f,0.f,0.f,0.f);
            if (gr < n) xv = ld4f(X + (size_t)gr*DD + k0 + lxk);
            Xs[lxr][lxk+0]=xv.x; Xs[lxr][lxk+1]=xv.y; Xs[lxr][lxk+2]=xv.z; Xs[lxr][lxk+3]=xv.w;
        }
        {
            float4 wv = ld4f(W + (size_t)(k0+lwk)*DD + col0 + lwc);
            Ws[lwk][lwc+0]=wv.x; Ws[lwk][lwc+1]=wv.y; Ws[lwk][lwc+2]=wv.z; Ws[lwk][lwc+3]=wv.w;
        }
        __syncthreads();
#pragma unroll
        for (int kk = 0; kk < 16; ++kk) {
            float a0=Xs[ty*4+0][kk], a1=Xs[ty*4+1][kk], a2=Xs[ty*4+2][kk], a3=Xs[ty*4+3][kk];
            float b0=Ws[kk][tx*4+0], b1=Ws[kk][tx*4+1], b2=Ws[kk][tx*4+2], b3=Ws[kk][tx*4+3];
            acc[0][0]+=a0*b0; acc[0][1]+=a0*b1; acc[0][2]+=a0*b2; acc[0][3]+=a0*b3;
            acc[1][0]+=a1*b0; acc[1][1]+=a1*b1; acc[1][2]+=a1*b2; acc[1][3]+=a1*b3;
            acc[2][0]+=a2*b0; acc[2][1]+=a2*b1; acc[2][2]+=a2*b2; acc[2][3]+=a2*b3;
            acc[3][0]+=a3*b0; acc[3][1]+=a3*b1; acc[3][2]+=a3*b2; acc[3][3]+=a3*b3;
        }
        __syncthreads();
    }
#pragma unroll
    for (int i = 0; i < 4; ++i) {
        int gr = row0 + ty*4 + i;
        if (gr >= n) continue;
#pragma unroll
        for (int j = 0; j < 4; ++j) {
            float v = acc[i][j];
            v = (v >= 0.f) ? v : 0.1f * v;
            size_t off = (size_t)gr*DD + col0 + tx*4 + j;
            Yf[off] = v;
            Yb[off] = f2bf(v);
        }
    }
}

// ---------- bf16 MFMA GEMM: Y = [leaky](Xb @ Wt^T)[*scale][+resid] ----------
// X: bf16 [n][256]; Wt: bf16 [256 n][256 k] (k-contiguous). 128x128 tile,
// 4 waves of 64x64 (4x4 of 16x16x32 MFMA). LDS stride 40 shorts (bank-safe b128).
template <bool LEAKY, bool SCALE, bool RESID, bool WF32, bool WBF16, bool QKV>
__global__ __launch_bounds__(256, 2) void gemm_mfma(
    const short* __restrict__ X,
    const short* __restrict__ W0, const short* __restrict__ W1, const short* __restrict__ W2,
    float* __restrict__ Yf,
    short* __restrict__ Yb0, short* __restrict__ Yb1, short* __restrict__ Yb2,
    const float* __restrict__ resid, const float* __restrict__ rowscale, int n)
{
    const short* W = W0;
    short* Yb = Yb0;
    if (QKV) {
        int z = blockIdx.z;
        W  = (z == 0) ? W0 : (z == 1) ? W1 : W2;
        Yb = (z == 0) ? Yb0 : (z == 1) ? Yb1 : Yb2;
    }
    __shared__ short Xs[128 * 40];
    __shared__ short Ws[128 * 40];
    const int t = threadIdx.x, lane = t & 63, wave = t >> 6;
    const int wm = (wave & 1) * 64, wn = (wave >> 1) * 64;
    const int row0 = blockIdx.x * 128, col0 = blockIdx.y * 128;
    const int l15 = lane & 15, lg = lane >> 4;

    f4v acc[16];
#pragma unroll
    for (int i = 0; i < 16; ++i) acc[i] = (f4v){0.f, 0.f, 0.f, 0.f};

    for (int k0 = 0; k0 < 256; k0 += 32) {
        __syncthreads();
#pragma unroll
        for (int i = 0; i < 2; ++i) {
            int c = t + i * 256;
            int r = c >> 2, kp = (c & 3) * 8;
            int gr = row0 + r;
            s8v xv = (s8v){0,0,0,0,0,0,0,0};
            if (gr < n) xv = *(const s8v*)(X + (size_t)gr * 256 + k0 + kp);
            *(s8v*)(Xs + r * 40 + kp) = xv;
            s8v wv = *(const s8v*)(W + (size_t)(col0 + r) * 256 + k0 + kp);
            *(s8v*)(Ws + r * 40 + kp) = wv;
        }
        __syncthreads();
        s8v af[4], bfr[4];
#pragma unroll
        for (int i = 0; i < 4; ++i) af[i]  = *(const s8v*)(Xs + (wm + i*16 + l15) * 40 + lg * 8);
#pragma unroll
        for (int j = 0; j < 4; ++j) bfr[j] = *(const s8v*)(Ws + (wn + j*16 + l15) * 40 + lg * 8);
#pragma unroll
        for (int i = 0; i < 4; ++i)
#pragma unroll
            for (int j = 0; j < 4; ++j)
                acc[i*4+j] = __builtin_amdgcn_mfma_f32_16x16x32_bf16(af[i], bfr[j], acc[i*4+j], 0, 0, 0);
    }

#pragma unroll
    for (int i = 0; i < 4; ++i) {
#pragma unroll
        for (int r = 0; r < 4; ++r) {
            int gr = row0 + wm + i*16 + lg*4 + r;
            if (gr >= n) continue;
            float sc = SCALE ? rowscale[gr] : 1.0f;
#pragma unroll
            for (int j = 0; j < 4; ++j) {
                int gc = col0 + wn + j*16 + l15;
                float v = acc[i*4+j][r];
                if (LEAKY) v = (v >= 0.f) ? v : 0.1f * v;
                if (SCALE) v *= sc;
                size_t off = (size_t)gr * 256 + gc;
                if (RESID) v += resid[off];
                if (WF32) Yf[off] = v;
                if (WBF16) Yb[off] = f2bf(v);
            }
        }
    }
}

// ---------- MFMA sigmoid attention: O = sum_tiles sigmoid(Q Kt^T) Vt ----------
// Block = (complex, q-group of 64 rows); 4 waves own one 16-row q-tile each.
// K staged natural (stride 264 shorts); V staged transposed + XOR-8 swizzled
// (stride 40). S goes C-layout -> LDS -> A-layout (bf16). Zero-filled OOB V
// rows make padded keys contribute exactly 0 (sigmoid(0)*0).
__global__ __launch_bounds__(256, 2) void attn_mfma(
    const short* __restrict__ Qb, const short* __restrict__ Kb, const short* __restrict__ Vb,
    short* __restrict__ Ob, const int* __restrict__ qs, const int* __restrict__ ks)
{
    __shared__ short Kl[32 * 264];
    __shared__ short Vt[256 * 40];
    __shared__ short Ss[4][16 * 40];
    const int b = blockIdx.x;
    const int q0 = qs[2*b], qc = qs[2*b+1];
    const int k0 = ks[2*b], kc = ks[2*b+1];
    if ((int)blockIdx.y * 64 >= qc) return;           // block-uniform exit
    const int t = threadIdx.x, lane = t & 63, wave = t >> 6;
    const int l15 = lane & 15, lg = lane >> 4;
    const int qtile = blockIdx.y * 4 + wave;
    const bool valid = qtile * 16 < qc;

    s8v qf[8];
    {
        int qr = qtile * 16 + l15;
        if (qr >= qc) qr = qc - 1;                     // clamp (results discarded)
        const short* qp = Qb + (size_t)(q0 + qr) * 256 + lg * 8;
#pragma unroll
        for (int s = 0; s < 8; ++s) qf[s] = *(const s8v*)(qp + s * 32);
    }
    f4v o[16];
#pragma unroll
    for (int i = 0; i < 16; ++i) o[i] = (f4v){0.f, 0.f, 0.f, 0.f};

    const int nkt = (kc + 31) >> 5;
    for (int kt = 0; kt < nkt; ++kt) {
        __syncthreads();
#pragma unroll
        for (int i = 0; i < 4; ++i) {
            int c = t + i * 256;                       // 0..1023
            int key = c >> 5, d0 = (c & 31) * 8;
            int gk = kt * 32 + key;
            s8v kv = (s8v){0,0,0,0,0,0,0,0}, vv = kv;
            if (gk < kc) {
                kv = *(const s8v*)(Kb + (size_t)(k0 + gk) * 256 + d0);
                vv = *(const s8v*)(Vb + (size_t)(k0 + gk) * 256 + d0);
            }
            *(s8v*)(Kl + key * 264 + d0) = kv;
#pragma unroll
            for (int j = 0; j < 8; ++j) {
                int d = d0 + j;
                int kcol = key ^ (((d >> 3) & 3) << 3);   // XOR-8 swizzle
                Vt[d * 40 + kcol] = vv[j];
            }
        }
        __syncthreads();
        if (valid) {
#pragma unroll
            for (int nt = 0; nt < 2; ++nt) {
                f4v s = (f4v){0.f, 0.f, 0.f, 0.f};
#pragma unroll
                for (int ss = 0; ss < 8; ++ss) {
                    s8v kb = *(const s8v*)(Kl + (nt*16 + l15) * 264 + ss * 32 + lg * 8);
                    s = __builtin_amdgcn_mfma_f32_16x16x32_bf16(qf[ss], kb, s, 0, 0, 0);
                }
#pragma unroll
                for (int r = 0; r < 4; ++r) {
                    float sv = 1.0f / (1.0f + __expf(-s[r]));
                    Ss[wave][(lg*4 + r) * 40 + nt*16 + l15] = f2bf(sv);
                }
            }
            __builtin_amdgcn_s_waitcnt(0xc07f);        // lgkmcnt(0): S write->read
            s8v sa = *(const s8v*)(&Ss[wave][0] + l15 * 40 + lg * 8);
#pragma unroll
            for (int nt = 0; nt < 16; ++nt) {
                int rowb = nt * 16 + l15;
                s8v vb = *(const s8v*)(Vt + rowb * 40 + (lg ^ ((rowb >> 3) & 3)) * 8);
                o[nt] = __builtin_amdgcn_mfma_f32_16x16x32_bf16(sa, vb, o[nt], 0, 0, 0);
            }
        }
    }
    if (valid) {
#pragma unroll
        for (int nt = 0; nt < 16; ++nt) {
#pragma unroll
            for (int r = 0; r < 4; ++r) {
                int qr = qtile * 16 + lg * 4 + r;
                if (qr < qc) Ob[(size_t)(q0 + qr) * 256 + nt*16 + l15] = f2bf(o[nt][r]);
            }
        }
    }
}

extern "C" void kernel_launch(void* const* d_in, const int* in_sizes, int n_in,
                              void* d_out, int out_size, void* d_ws, size_t ws_size,
                              hipStream_t stream)
{
    const float* fatoms = (const float*)d_in[0];
    const float* fres   = (const float*)d_in[1];
    const float* Wlig   = (const float*)d_in[2];
    const float* Wres   = (const float*)d_in[3];
    const int* lig_raw  = (const int*)d_in[12];
    const int* res_raw  = (const int*)d_in[13];
    const int nA = in_sizes[0] / DD;
    const int nR = in_sizes[1] / DD;
    (void)n_in; (void)out_size; (void)ws_size;

    char* p = (char*)d_ws;
    auto carve = [&](size_t bytes) -> void* {
        void* r = (void*)p;
        p += (bytes + 255) & ~(size_t)255;
        return r;
    };
    float* A  = (float*)carve((size_t)nA * DD * 4);
    float* R  = (float*)carve((size_t)nR * DD * 4);
    short* Ab = (short*)carve((size_t)nA * DD * 2);
    short* Rb = (short*)carve((size_t)nR * DD * 2);
    short* AQ = (short*)carve((size_t)nA * DD * 2);   // becomes attn out T_A
    short* AK = (short*)carve((size_t)nA * DD * 2);
    short* AV = (short*)carve((size_t)nA * DD * 2);
    short* RQ = (short*)carve((size_t)nR * DD * 2);   // becomes attn out T_R
    short* RK = (short*)carve((size_t)nR * DD * 2);
    short* RV = (short*)carve((size_t)nR * DD * 2);
    float* sA = (float*)carve((size_t)nA * 4);
    float* sR = (float*)carve((size_t)nR * 4);
    int* ligN = (int*)carve(NCPLX * 2 * 4);
    int* resN = (int*)carve(NCPLX * 2 * 4);
    short* Wt = (short*)carve((size_t)8 * 65536 * 2);  // 8 transposed bf16 weights

    const short* WQlT = Wt + 0*65536; const short* WKlT = Wt + 1*65536;
    const short* WVlT = Wt + 2*65536; const short* WOlT = Wt + 3*65536;
    const short* WQrT = Wt + 4*65536; const short* WKrT = Wt + 5*65536;
    const short* WVrT = Wt + 6*65536; const short* WOrT = Wt + 7*65536;

    float* out = (float*)d_out;
    const dim3 blk(256);
    const int gA128 = (nA + 127) / 128, gR128 = (nR + 127) / 128;

    conv_scope<<<1, NCPLX, 0, stream>>>(lig_raw, res_raw, nA, nR, ligN, resN);
    scales_k<<<NCPLX, 256, 0, stream>>>(ligN, resN, sA, sR);
    wtrans<<<dim3(8, 64), blk, 0, stream>>>(
        (const float*)d_in[4], (const float*)d_in[5], (const float*)d_in[6], (const float*)d_in[7],
        (const float*)d_in[8], (const float*)d_in[9], (const float*)d_in[10], (const float*)d_in[11], Wt);

    gemm_xform<<<dim3((nA+63)/64, 4), blk, 0, stream>>>(fatoms, Wlig, A, Ab, nA);
    gemm_xform<<<dim3((nR+63)/64, 4), blk, 0, stream>>>(fres,   Wres, R, Rb, nR);

    for (int it = 0; it < NITER; ++it) {
        // fused QKV projections (grid.z selects W / out)
        gemm_mfma<false,false,false,false,true,true><<<dim3(gA128, 2, 3), blk, 0, stream>>>(
            Ab, WQlT, WKlT, WVlT, nullptr, AQ, AK, AV, nullptr, nullptr, nA);
        gemm_mfma<false,false,false,false,true,true><<<dim3(gR128, 2, 3), blk, 0, stream>>>(
            Rb, WQrT, WKrT, WVrT, nullptr, RQ, RK, RV, nullptr, nullptr, nR);

        attn_mfma<<<dim3(NCPLX, 1), blk, 0, stream>>>(AQ, RK, RV, AQ, ligN, resN);
        attn_mfma<<<dim3(NCPLX, 8), blk, 0, stream>>>(RQ, AK, AV, RQ, resN, ligN);

        if (it < NITER - 1) {
            gemm_mfma<true,true,true,true,true,false><<<dim3(gA128, 2, 1), blk, 0, stream>>>(
                AQ, WOlT, nullptr, nullptr, A, Ab, nullptr, nullptr, A, sA, nA);
            gemm_mfma<true,true,true,true,true,false><<<dim3(gR128, 2, 1), blk, 0, stream>>>(
                RQ, WOrT, nullptr, nullptr, R, Rb, nullptr, nullptr, R, sR, nR);
        } else {
            gemm_mfma<true,true,true,true,false,false><<<dim3(gA128, 2, 1), blk, 0, stream>>>(
                AQ, WOlT, nullptr, nullptr, out, nullptr, nullptr, nullptr, A, sA, nA);
            gemm_mfma<true,true,true,true,false,false><<<dim3(gR128, 2, 1), blk, 0, stream>>>(
                RQ, WOrT, nullptr, nullptr, out + (size_t)nA * DD, nullptr, nullptr, nullptr, R, sR, nR);
        }
    }
}

// Round 4
// 1058.839 us; speedup vs baseline: 4.5364x; 1.0847x over previous
//
#include <hip/hip_runtime.h>
#include <hip/hip_bf16.h>

// ProteinLigandAttention: D=256, B=256, 3 iters.
// fp32 state (accuracy) + bf16 MFMA for ALL matmuls (input xform included —
// MFMA accumulates fp32; only input rounding is bf16, ~0.01 abs error).
// QKV = one N=768 GEMM (weights + outputs contiguous), col-tile on blockIdx.x
// for L2 reuse of X across column blocks.

#define DD 256
#define NCPLX 256
#define NITER 3

using s8v = __attribute__((ext_vector_type(8))) short;   // 8 bf16 = 4 VGPR
using f4v = __attribute__((ext_vector_type(4))) float;   // MFMA C/D

__device__ __forceinline__ short f2bf(float f) {
    union { float f; unsigned u; } v; v.f = f;
    unsigned r = v.u + 0x7fffu + ((v.u >> 16) & 1u);   // RNE
    return (short)(r >> 16);
}
__device__ __forceinline__ float4 ld4f(const float* p) { return *reinterpret_cast<const float4*>(p); }

// ---------- scope normalization (int32 vs int64) ----------
__global__ void conv_scope(const int* __restrict__ lig, const int* __restrict__ res,
                           int nA, int nR, int* __restrict__ ligN, int* __restrict__ resN)
{
    const int b = threadIdx.x;
    const bool l64 = (lig[2*(NCPLX-1)] + lig[2*(NCPLX-1)+1]) != nA;
    const bool r64 = (res[2*(NCPLX-1)] + res[2*(NCPLX-1)+1]) != nR;
    ligN[2*b]   = l64 ? lig[4*b]   : lig[2*b];
    ligN[2*b+1] = l64 ? lig[4*b+2] : lig[2*b+1];
    resN[2*b]   = r64 ? res[4*b]   : res[2*b];
    resN[2*b+1] = r64 ? res[4*b+2] : res[2*b+1];
}

__global__ void scales_k(const int* __restrict__ lig, const int* __restrict__ res,
                         float* __restrict__ sA, float* __restrict__ sR)
{
    int b = blockIdx.x, t = threadIdx.x;
    int a0 = lig[2*b], ac = lig[2*b+1];
    int r0 = res[2*b], rc = res[2*b+1];
    float va = 1.0f / (float)rc, vr = 1.0f / (float)ac;
    for (int i = t; i < ac; i += blockDim.x) sA[a0+i] = va;
    for (int i = t; i < rc; i += blockDim.x) sR[r0+i] = vr;
}

// ---------- one-time weight convert+transpose: Wt[n][k] bf16, 10 weights ----------
// Layout: 0=WQl 1=WKl 2=WVl 3=WOl 4=WQr 5=WKr 6=WVr 7=WOr 8=Wlig 9=Wres
__global__ __launch_bounds__(256) void wtrans(
    const float* w0, const float* w1, const float* w2, const float* w3,
    const float* w4, const float* w5, const float* w6, const float* w7,
    const float* w8, const float* w9, short* __restrict__ out)
{
    const float* W;
    switch (blockIdx.x) {
        case 0: W = w0; break; case 1: W = w1; break; case 2: W = w2; break;
        case 3: W = w3; break; case 4: W = w4; break; case 5: W = w5; break;
        case 6: W = w6; break; case 7: W = w7; break; case 8: W = w8; break;
        default: W = w9; break;
    }
    short* O = out + (size_t)blockIdx.x * 65536;
    const int tile = blockIdx.y;             // 64 tiles of 32x32
    const int tr = (tile >> 3) * 32, tc = (tile & 7) * 32;
    __shared__ short T[32 * 34];
    const int t = threadIdx.x;
#pragma unroll
    for (int i = 0; i < 4; ++i) {
        int idx = t + i * 256, r = idx >> 5, c = idx & 31;
        T[c * 34 + r] = f2bf(W[(size_t)(tr + r) * 256 + tc + c]);
    }
    __syncthreads();
#pragma unroll
    for (int i = 0; i < 4; ++i) {
        int idx = t + i * 256, nn = idx >> 5, kk = idx & 31;
        O[(size_t)(tc + nn) * 256 + tr + kk] = T[nn * 34 + kk];
    }
}

// ---------- unified bf16 MFMA GEMM ----------
// Y = [leaky](X @ Wt^T)[*scale][+resid]; X fp32 (converted in staging) or bf16.
// Wt: [NBUF*256 n][256 k] k-contiguous. Grid: x = col tile (fast: L2 reuse of
// X rows), y = row tile. 128x128 tile, 4 waves of 64x64. LDS stride 40 shorts.
// NBUF=3: virtual N=768, output buffer decoded as gc>>8 (stride bufstride).
template <bool XF32, bool LEAKY, bool SCALE, bool RESID, bool WF32, bool WBF16, int NBUF>
__global__ __launch_bounds__(256, 2) void gemm_mfma(
    const void* __restrict__ Xv, const short* __restrict__ W,
    float* __restrict__ Yf, short* __restrict__ Yb, size_t bufstride,
    const float* __restrict__ resid, const float* __restrict__ rowscale, int n)
{
    __shared__ short Xs[128 * 40];
    __shared__ short Ws[128 * 40];
    const int t = threadIdx.x, lane = t & 63, wave = t >> 6;
    const int wm = (wave & 1) * 64, wn = (wave >> 1) * 64;
    const int col0 = blockIdx.x * 128, row0 = blockIdx.y * 128;
    const int l15 = lane & 15, lg = lane >> 4;

    f4v acc[16];
#pragma unroll
    for (int i = 0; i < 16; ++i) acc[i] = (f4v){0.f, 0.f, 0.f, 0.f};

    for (int k0 = 0; k0 < 256; k0 += 32) {
        __syncthreads();
        if (XF32) {
            const float* X = (const float*)Xv;
#pragma unroll
            for (int i = 0; i < 4; ++i) {
                int idx = t + i * 256;               // 0..1023
                int r = idx >> 3, kp = (idx & 7) * 4;
                int gr = row0 + r;
                float4 xv = make_float4(0.f, 0.f, 0.f, 0.f);
                if (gr < n) xv = ld4f(X + (size_t)gr * 256 + k0 + kp);
                short4 s4;
                s4.x = f2bf(xv.x); s4.y = f2bf(xv.y); s4.z = f2bf(xv.z); s4.w = f2bf(xv.w);
                *(short4*)(Xs + r * 40 + kp) = s4;
            }
        } else {
            const short* X = (const short*)Xv;
#pragma unroll
            for (int i = 0; i < 2; ++i) {
                int c = t + i * 256;
                int r = c >> 2, kp = (c & 3) * 8;
                int gr = row0 + r;
                s8v xv = (s8v){0,0,0,0,0,0,0,0};
                if (gr < n) xv = *(const s8v*)(X + (size_t)gr * 256 + k0 + kp);
                *(s8v*)(Xs + r * 40 + kp) = xv;
            }
        }
#pragma unroll
        for (int i = 0; i < 2; ++i) {
            int c = t + i * 256;
            int r = c >> 2, kp = (c & 3) * 8;
            s8v wv = *(const s8v*)(W + (size_t)(col0 + r) * 256 + k0 + kp);
            *(s8v*)(Ws + r * 40 + kp) = wv;
        }
        __syncthreads();
        s8v af[4], bfr[4];
#pragma unroll
        for (int i = 0; i < 4; ++i) af[i]  = *(const s8v*)(Xs + (wm + i*16 + l15) * 40 + lg * 8);
#pragma unroll
        for (int j = 0; j < 4; ++j) bfr[j] = *(const s8v*)(Ws + (wn + j*16 + l15) * 40 + lg * 8);
#pragma unroll
        for (int i = 0; i < 4; ++i)
#pragma unroll
            for (int j = 0; j < 4; ++j)
                acc[i*4+j] = __builtin_amdgcn_mfma_f32_16x16x32_bf16(af[i], bfr[j], acc[i*4+j], 0, 0, 0);
    }

#pragma unroll
    for (int i = 0; i < 4; ++i) {
#pragma unroll
        for (int r = 0; r < 4; ++r) {
            int gr = row0 + wm + i*16 + lg*4 + r;
            if (gr >= n) continue;
            float sc = SCALE ? rowscale[gr] : 1.0f;
#pragma unroll
            for (int j = 0; j < 4; ++j) {
                int gcv = col0 + wn + j*16 + l15;
                float v = acc[i*4+j][r];
                if (LEAKY) v = (v >= 0.f) ? v : 0.1f * v;
                if (SCALE) v *= sc;
                if (NBUF == 1) {
                    size_t off = (size_t)gr * 256 + gcv;
                    if (RESID) v += resid[off];
                    if (WF32) Yf[off] = v;
                    if (WBF16) Yb[off] = f2bf(v);
                } else {
                    size_t off = (size_t)(gcv >> 8) * bufstride + (size_t)gr * 256 + (gcv & 255);
                    if (WBF16) Yb[off] = f2bf(v);
                }
            }
        }
    }
}

// ---------- MFMA sigmoid attention: O = sum_tiles sigmoid(Q Kt^T) Vt ----------
__global__ __launch_bounds__(256, 2) void attn_mfma(
    const short* __restrict__ Qb, const short* __restrict__ Kb, const short* __restrict__ Vb,
    short* __restrict__ Ob, const int* __restrict__ qs, const int* __restrict__ ks)
{
    __shared__ short Kl[32 * 264];
    __shared__ short Vt[256 * 40];
    __shared__ short Ss[4][16 * 40];
    const int b = blockIdx.x;
    const int q0 = qs[2*b], qc = qs[2*b+1];
    const int k0 = ks[2*b], kc = ks[2*b+1];
    if ((int)blockIdx.y * 64 >= qc) return;           // block-uniform exit
    const int t = threadIdx.x, lane = t & 63, wave = t >> 6;
    const int l15 = lane & 15, lg = lane >> 4;
    const int qtile = blockIdx.y * 4 + wave;
    const bool valid = qtile * 16 < qc;

    s8v qf[8];
    {
        int qr = qtile * 16 + l15;
        if (qr >= qc) qr = qc - 1;                     // clamp (results discarded)
        const short* qp = Qb + (size_t)(q0 + qr) * 256 + lg * 8;
#pragma unroll
        for (int s = 0; s < 8; ++s) qf[s] = *(const s8v*)(qp + s * 32);
    }
    f4v o[16];
#pragma unroll
    for (int i = 0; i < 16; ++i) o[i] = (f4v){0.f, 0.f, 0.f, 0.f};

    const int nkt = (kc + 31) >> 5;
    for (int kt = 0; kt < nkt; ++kt) {
        __syncthreads();
#pragma unroll
        for (int i = 0; i < 4; ++i) {
            int c = t + i * 256;                       // 0..1023
            int key = c >> 5, d0 = (c & 31) * 8;
            int gk = kt * 32 + key;
            s8v kv = (s8v){0,0,0,0,0,0,0,0}, vv = kv;
            if (gk < kc) {
                kv = *(const s8v*)(Kb + (size_t)(k0 + gk) * 256 + d0);
                vv = *(const s8v*)(Vb + (size_t)(k0 + gk) * 256 + d0);
            }
            *(s8v*)(Kl + key * 264 + d0) = kv;
#pragma unroll
            for (int j = 0; j < 8; ++j) {
                int d = d0 + j;
                int kcol = key ^ (((d >> 3) & 3) << 3);   // XOR-8 swizzle
                Vt[d * 40 + kcol] = vv[j];
            }
        }
        __syncthreads();
        if (valid) {
#pragma unroll
            for (int nt = 0; nt < 2; ++nt) {
                f4v s = (f4v){0.f, 0.f, 0.f, 0.f};
#pragma unroll
                for (int ss = 0; ss < 8; ++ss) {
                    s8v kb = *(const s8v*)(Kl + (nt*16 + l15) * 264 + ss * 32 + lg * 8);
                    s = __builtin_amdgcn_mfma_f32_16x16x32_bf16(qf[ss], kb, s, 0, 0, 0);
                }
#pragma unroll
                for (int r = 0; r < 4; ++r) {
                    float sv = 1.0f / (1.0f + __expf(-s[r]));
                    Ss[wave][(lg*4 + r) * 40 + nt*16 + l15] = f2bf(sv);
                }
            }
            __builtin_amdgcn_s_waitcnt(0xc07f);        // lgkmcnt(0): S write->read
            s8v sa = *(const s8v*)(&Ss[wave][0] + l15 * 40 + lg * 8);
#pragma unroll
            for (int nt = 0; nt < 16; ++nt) {
                int rowb = nt * 16 + l15;
                s8v vb = *(const s8v*)(Vt + rowb * 40 + (lg ^ ((rowb >> 3) & 3)) * 8);
                o[nt] = __builtin_amdgcn_mfma_f32_16x16x32_bf16(sa, vb, o[nt], 0, 0, 0);
            }
        }
    }
    if (valid) {
#pragma unroll
        for (int nt = 0; nt < 16; ++nt) {
#pragma unroll
            for (int r = 0; r < 4; ++r) {
                int qr = qtile * 16 + lg * 4 + r;
                if (qr < qc) Ob[(size_t)(q0 + qr) * 256 + nt*16 + l15] = f2bf(o[nt][r]);
            }
        }
    }
}

extern "C" void kernel_launch(void* const* d_in, const int* in_sizes, int n_in,
                              void* d_out, int out_size, void* d_ws, size_t ws_size,
                              hipStream_t stream)
{
    const float* fatoms = (const float*)d_in[0];
    const float* fres   = (const float*)d_in[1];
    const int* lig_raw  = (const int*)d_in[12];
    const int* res_raw  = (const int*)d_in[13];
    const int nA = in_sizes[0] / DD;
    const int nR = in_sizes[1] / DD;
    (void)n_in; (void)out_size; (void)ws_size;

    char* p = (char*)d_ws;
    auto carve = [&](size_t bytes) -> void* {
        void* r = (void*)p;
        p += (bytes + 255) & ~(size_t)255;
        return r;
    };
    float* A  = (float*)carve((size_t)nA * DD * 4);
    float* R  = (float*)carve((size_t)nR * DD * 4);
    short* Ab = (short*)carve((size_t)nA * DD * 2);
    short* Rb = (short*)carve((size_t)nR * DD * 2);
    short* AQ = (short*)carve((size_t)nA * DD * 2);   // AQ,AK,AV contiguous (QKV decode)
    short* AK = (short*)carve((size_t)nA * DD * 2);
    short* AV = (short*)carve((size_t)nA * DD * 2);
    short* RQ = (short*)carve((size_t)nR * DD * 2);   // RQ,RK,RV contiguous
    short* RK = (short*)carve((size_t)nR * DD * 2);
    short* RV = (short*)carve((size_t)nR * DD * 2);
    float* sA = (float*)carve((size_t)nA * 4);
    float* sR = (float*)carve((size_t)nR * 4);
    int* ligN = (int*)carve(NCPLX * 2 * 4);
    int* resN = (int*)carve(NCPLX * 2 * 4);
    short* Wt = (short*)carve((size_t)10 * 65536 * 2); // 10 transposed bf16 weights
    (void)AK; (void)AV; (void)RK; (void)RV;

    const short* WqkvL = Wt + 0*65536;   // QKl,WKl,WVl contiguous (N=768)
    const short* WOlT  = Wt + 3*65536;
    const short* WqkvR = Wt + 4*65536;   // QKr,WKr,WVr contiguous
    const short* WOrT  = Wt + 7*65536;
    const short* WligT = Wt + 8*65536;
    const short* WresT = Wt + 9*65536;

    float* out = (float*)d_out;
    const dim3 blk(256);
    const int gA = (nA + 127) / 128, gR = (nR + 127) / 128;
    const size_t bsA = (size_t)nA * DD, bsR = (size_t)nR * DD;

    conv_scope<<<1, NCPLX, 0, stream>>>(lig_raw, res_raw, nA, nR, ligN, resN);
    scales_k<<<NCPLX, 256, 0, stream>>>(ligN, resN, sA, sR);
    wtrans<<<dim3(10, 64), blk, 0, stream>>>(
        (const float*)d_in[4], (const float*)d_in[5], (const float*)d_in[6], (const float*)d_in[7],
        (const float*)d_in[8], (const float*)d_in[9], (const float*)d_in[10], (const float*)d_in[11],
        (const float*)d_in[2], (const float*)d_in[3], Wt);

    // input transforms (fp32 X converted in staging; fp32 state + bf16 shadow)
    gemm_mfma<true,true,false,false,true,true,1><<<dim3(2, gA), blk, 0, stream>>>(
        fatoms, WligT, A, Ab, 0, nullptr, nullptr, nA);
    gemm_mfma<true,true,false,false,true,true,1><<<dim3(2, gR), blk, 0, stream>>>(
        fres, WresT, R, Rb, 0, nullptr, nullptr, nR);

    for (int it = 0; it < NITER; ++it) {
        // fused QKV projections: one N=768 GEMM per side
        gemm_mfma<false,false,false,false,false,true,3><<<dim3(6, gA), blk, 0, stream>>>(
            Ab, WqkvL, nullptr, AQ, bsA, nullptr, nullptr, nA);
        gemm_mfma<false,false,false,false,false,true,3><<<dim3(6, gR), blk, 0, stream>>>(
            Rb, WqkvR, nullptr, RQ, bsR, nullptr, nullptr, nR);

        attn_mfma<<<dim3(NCPLX, 1), blk, 0, stream>>>(AQ, RK, RV, AQ, ligN, resN);
        attn_mfma<<<dim3(NCPLX, 8), blk, 0, stream>>>(RQ, AK, AV, RQ, resN, ligN);

        if (it < NITER - 1) {
            gemm_mfma<false,true,true,true,true,true,1><<<dim3(2, gA), blk, 0, stream>>>(
                AQ, WOlT, A, Ab, 0, A, sA, nA);
            gemm_mfma<false,true,true,true,true,true,1><<<dim3(2, gR), blk, 0, stream>>>(
                RQ, WOrT, R, Rb, 0, R, sR, nR);
        } else {
            gemm_mfma<false,true,true,true,true,false,1><<<dim3(2, gA), blk, 0, stream>>>(
                AQ, WOlT, out, nullptr, 0, A, sA, nA);
            gemm_mfma<false,true,true,true,true,false,1><<<dim3(2, gR), blk, 0, stream>>>(
                RQ, WOrT, out + bsA, nullptr, 0, R, sR, nR);
        }
    }
}